// Round 16
// baseline (65.038 us; speedup 1.0000x reference)
//
#include <hip/hip_runtime.h>
#include <hip/hip_fp16.h>

typedef _Float16 half_t;
typedef _Float16 f16x8 __attribute__((ext_vector_type(8)));
typedef __fp16 fp16x2 __attribute__((ext_vector_type(2)));
typedef float f32x4 __attribute__((ext_vector_type(4)));

#define MFMA_F16(a, b, c) __builtin_amdgcn_mfma_f32_16x16x32_f16((a), (b), (c), 0, 0, 0)

static __device__ inline unsigned pkrtz(float a, float b) {
    union { fp16x2 h; unsigned u; } c;
    c.h = __builtin_amdgcn_cvt_pkrtz(a, b);
    return c.u;
}

// ---------------------------------------------------------------------------
// prep (80 blocks):
//   0..47 : W3 = (rw@qw)^T fp16 regrouped [8 heads][96 rows=q|k|v][512];
//           q rows scaled by 0.125*log2(e)
//   48..79: pw_t = proj_w^T fp16 [512][256]
// ---------------------------------------------------------------------------
__global__ __launch_bounds__(256) void prep(
    const float* __restrict__ qw, const float* __restrict__ rw,
    const float* __restrict__ pw, half_t* __restrict__ pw_t,
    half_t* __restrict__ W3) {
    __shared__ __align__(16) char smem[24576];
    const int bid = blockIdx.x, tid = threadIdx.x;

    if (bid < 48) {
        // W[n][k] = sum_c qw[c][n]*scale(n) * rw[k][c]; M=768,N=512,K=256
        char* As = smem;
        char* Bs = smem + 8192;
        const int M0 = (bid % 12) * 64, N0 = (bid / 12) * 128;
        const int lane = tid & 63, w = tid >> 6;
        const int l15 = lane & 15, l4 = lane >> 4;
        const int wrow = (w >> 1) * 32, wcol = (w & 1) * 64;
        const int pa = (l15 & 7) << 4;

        f32x4 acc[2][4];
#pragma unroll
        for (int i = 0; i < 2; ++i)
#pragma unroll
            for (int j = 0; j < 4; ++j) acc[i][j] = (f32x4){0.f, 0.f, 0.f, 0.f};

        for (int kc = 0; kc < 4; ++kc) {
            int c0 = kc * 64;
            __syncthreads();
#pragma unroll
            for (int i = 0; i < 2; ++i) {
                int j = tid + i * 256;
                int row = j >> 3, e8 = (j & 7) * 8;
                float s = (M0 + row) < 256 ? 0.18033688f : 1.f;  // 0.125*log2e
                f16x8 v;
#pragma unroll
                for (int e = 0; e < 8; ++e)
                    v[e] = (half_t)(qw[(size_t)(c0 + e8 + e) * 768 + M0 + row] * s);
                *(f16x8*)(As + row * 128 + ((e8 * 2) ^ ((row & 7) << 4))) = v;
            }
#pragma unroll
            for (int i = 0; i < 4; ++i) {
                int j = tid + i * 256;
                int row = j >> 3, e8 = (j & 7) * 8;
                const float* p = rw + (size_t)(N0 + row) * 256 + c0 + e8;
                float4 u0 = *(const float4*)p;
                float4 u1 = *(const float4*)(p + 4);
                f16x8 v;
                v[0] = (half_t)u0.x; v[1] = (half_t)u0.y;
                v[2] = (half_t)u0.z; v[3] = (half_t)u0.w;
                v[4] = (half_t)u1.x; v[5] = (half_t)u1.y;
                v[6] = (half_t)u1.z; v[7] = (half_t)u1.w;
                *(f16x8*)(Bs + row * 128 + ((e8 * 2) ^ ((row & 7) << 4))) = v;
            }
            __syncthreads();
#pragma unroll
            for (int ki = 0; ki < 2; ++ki) {
                f16x8 af[2], bf[4];
#pragma unroll
                for (int mi = 0; mi < 2; ++mi) {
                    int row = wrow + mi * 16 + l15;
                    af[mi] = *(const f16x8*)(As + row * 128 + (((ki * 4 + l4) << 4) ^ pa));
                }
#pragma unroll
                for (int nj = 0; nj < 4; ++nj) {
                    int row = wcol + nj * 16 + l15;
                    bf[nj] = *(const f16x8*)(Bs + row * 128 + (((ki * 4 + l4) << 4) ^ pa));
                }
#pragma unroll
                for (int mi = 0; mi < 2; ++mi)
#pragma unroll
                    for (int nj = 0; nj < 4; ++nj)
                        acc[mi][nj] = MFMA_F16(af[mi], bf[nj], acc[mi][nj]);
            }
        }
#pragma unroll
        for (int mi = 0; mi < 2; ++mi)
#pragma unroll
            for (int nj = 0; nj < 4; ++nj)
#pragma unroll
                for (int reg = 0; reg < 4; ++reg) {
                    int n = M0 + wrow + mi * 16 + l4 * 4 + reg;   // qkv output col
                    int gcol = N0 + wcol + nj * 16 + l15;          // k index
                    int part = n >> 8, hh = (n & 255) >> 5, dd = n & 31;
                    W3[(size_t)(hh * 96 + part * 32 + dd) * 512 + gcol] =
                        (half_t)acc[mi][nj][reg];
                }
        return;
    }

    // pw transpose
    half_t* tile = (half_t*)smem;  // [64][72]
    int t = bid - 48;
    int R0 = (t >> 3) * 64, C0 = (t & 7) * 64;
#pragma unroll
    for (int e = 0; e < 16; ++e) {
        int idx = tid + e * 256;
        int r = idx >> 6, c = idx & 63;
        tile[r * 72 + c] = (half_t)pw[(size_t)(R0 + r) * 512 + C0 + c];
    }
    __syncthreads();
#pragma unroll
    for (int e = 0; e < 16; ++e) {
        int idx = tid + e * 256;
        int c = idx >> 6, r = idx & 63;
        pw_t[(size_t)(C0 + c) * 256 + R0 + r] = tile[r * 72 + c];
    }
}

// ---------------------------------------------------------------------------
// FUSED qkv-GEMM + block-diagonal attention. One 512-thread WG per
// (b,h,blk); bid = h*64 + (b*16+blk) so the 8 head-WGs of a block sit on
// the SAME XCD (Δbid=64 ≡ 0 mod 8) and share the 512KB x-tile via L2.
// Phase 1: qkv_head = x_rows[256x512 fp32] @ W3[h][96][512]^T, 8 waves,
//          wave w owns rows w*32 (= its attention q-rows). BK=64,
//          reg-staged prefetch, As 32KB + Bs 12KB.
// Phase 2: handoff through LDS (q[256][32] k[256][32] V^T[32][264]
//          overlaid on dead staging space; 49KB peak).
// Phase 3: attention (swapped QK^T, exp2, unnormalized PV, final div).
// ---------------------------------------------------------------------------
__global__ __launch_bounds__(512, 4) void qkv_attn(
    const float* __restrict__ X, const half_t* __restrict__ W3,
    half_t* __restrict__ o_ws) {
    __shared__ __align__(16) char smem[50176];
    char* As = smem;            // [256 rows][128B]  (GEMM phase)
    char* Bs = smem + 32768;    // [96 rows][128B]
    half_t* q_lds = (half_t*)smem;             // [256][32] 16KB (attn phase)
    half_t* k_lds = (half_t*)(smem + 16384);   // [256][32] 16KB
    half_t* vT    = (half_t*)(smem + 32768);   // [32][264] 16.9KB

    const int bid = blockIdx.x;
    const int h = bid >> 6, gb = bid & 63, b = gb >> 4, blk = gb & 15;
    const int tid = threadIdx.x, lane = tid & 63, w = tid >> 6;
    const int l15 = lane & 15, l4 = lane >> 4;
    const int pa = (l15 & 7) << 4;

    const float* Xt = X + (size_t)(b * 4096 + blk * 256) * 512;
    const half_t* Bh = W3 + (size_t)h * 96 * 512;

    // ---------------- Phase 1: GEMM ----------------
    f32x4 acc[2][6];
#pragma unroll
    for (int i = 0; i < 2; ++i)
#pragma unroll
        for (int j = 0; j < 6; ++j) acc[i][j] = (f32x4){0.f, 0.f, 0.f, 0.f};

    f16x8 aReg[4], bReg[2];

    auto load_tile = [&](int kt) {
#pragma unroll
        for (int i = 0; i < 4; ++i) {
            int J = tid + i * 512;
            int row = J >> 3, c = (J & 7) ^ (row & 7);
            const float* p = Xt + (size_t)row * 512 + kt * 64 + c * 8;
            float4 u0 = *(const float4*)p;
            float4 u1 = *(const float4*)(p + 4);
            f16x8 v;
            v[0] = (half_t)u0.x; v[1] = (half_t)u0.y;
            v[2] = (half_t)u0.z; v[3] = (half_t)u0.w;
            v[4] = (half_t)u1.x; v[5] = (half_t)u1.y;
            v[6] = (half_t)u1.z; v[7] = (half_t)u1.w;
            aReg[i] = v;
        }
        {
            int J = tid;
            int row = J >> 3, c = (J & 7) ^ (row & 7);
            bReg[0] = *(const f16x8*)(Bh + (size_t)row * 512 + kt * 64 + c * 8);
        }
        if (tid < 256) {
            int J = 512 + tid;
            int row = J >> 3, c = (J & 7) ^ (row & 7);
            bReg[1] = *(const f16x8*)(Bh + (size_t)row * 512 + kt * 64 + c * 8);
        }
    };

    load_tile(0);
    for (int kt = 0; kt < 8; ++kt) {
        __syncthreads();
#pragma unroll
        for (int i = 0; i < 4; ++i) {
            int J = tid + i * 512;
            *(f16x8*)(As + J * 16) = aReg[i];
        }
        *(f16x8*)(Bs + tid * 16) = bReg[0];
        if (tid < 256) *(f16x8*)(Bs + (512 + tid) * 16) = bReg[1];
        __syncthreads();
        if (kt + 1 < 8) load_tile(kt + 1);
#pragma unroll
        for (int ki = 0; ki < 2; ++ki) {
            f16x8 af[2], bf[6];
#pragma unroll
            for (int mi = 0; mi < 2; ++mi) {
                int row = w * 32 + mi * 16 + l15;
                af[mi] = *(const f16x8*)(As + row * 128 + (((ki * 4 + l4) << 4) ^ pa));
            }
#pragma unroll
            for (int nj = 0; nj < 6; ++nj) {
                int row = nj * 16 + l15;
                bf[nj] = *(const f16x8*)(Bs + row * 128 + (((ki * 4 + l4) << 4) ^ pa));
            }
#pragma unroll
            for (int mi = 0; mi < 2; ++mi)
#pragma unroll
                for (int nj = 0; nj < 6; ++nj)
                    acc[mi][nj] = MFMA_F16(af[mi], bf[nj], acc[mi][nj]);
        }
    }

    // ---------------- Phase 2: handoff to LDS ----------------
    __syncthreads();  // all waves done reading As/Bs
#pragma unroll
    for (int mi = 0; mi < 2; ++mi) {
#pragma unroll
        for (int nj = 0; nj < 6; ++nj) {
#pragma unroll
            for (int reg = 0; reg < 4; ++reg) {
                int row = w * 32 + mi * 16 + l4 * 4 + reg;
                int col = nj * 16 + l15;
                half_t hv = (half_t)acc[mi][nj][reg];
                if (col < 32) q_lds[row * 32 + col] = hv;
                else if (col < 64) k_lds[row * 32 + (col - 32)] = hv;
                else vT[(col - 64) * 264 + row] = hv;
            }
        }
    }
    __syncthreads();

    // ---------------- Phase 3: attention ----------------
    const int qb = w * 32;
    f16x8 aq[2];
    aq[0] = *(const f16x8*)&q_lds[(qb + l15) * 32 + l4 * 8];
    aq[1] = *(const f16x8*)&q_lds[(qb + 16 + l15) * 32 + l4 * 8];

    float s_run[2] = {0.f, 0.f};
    f32x4 acc_o[2][2];
#pragma unroll
    for (int qg = 0; qg < 2; ++qg)
#pragma unroll
        for (int fo = 0; fo < 2; ++fo) acc_o[qg][fo] = (f32x4){0.f, 0.f, 0.f, 0.f};
    const f32x4 zero4 = (f32x4){0.f, 0.f, 0.f, 0.f};

    for (int kt = 0; kt < 4; ++kt) {
        f16x8 ka[4];
#pragma unroll
        for (int t = 0; t < 4; ++t)
            ka[t] = *(const f16x8*)&k_lds[(kt * 64 + t * 16 + l15) * 32 + l4 * 8];
        f16x8 bv[2][2];
#pragma unroll
        for (int c = 0; c < 2; ++c)
#pragma unroll
            for (int fo = 0; fo < 2; ++fo)
                bv[c][fo] = *(const f16x8*)&vT[(fo * 16 + l15) * 264 + kt * 64 + c * 32 + l4 * 8];

        f32x4 st[2][4];
        __builtin_amdgcn_s_setprio(1);
#pragma unroll
        for (int qg = 0; qg < 2; ++qg)
#pragma unroll
            for (int t = 0; t < 4; ++t) st[qg][t] = MFMA_F16(ka[t], aq[qg], zero4);
        __builtin_amdgcn_s_setprio(0);

#pragma unroll
        for (int qg = 0; qg < 2; ++qg) {
            float p[4][4];
            float ps = 0.f;
#pragma unroll
            for (int t = 0; t < 4; ++t)
#pragma unroll
                for (int r = 0; r < 4; ++r) {
                    float e = exp2f(st[qg][t][r]);
                    p[t][r] = e;
                    ps += e;
                }
            ps += __shfl_xor(ps, 16);
            ps += __shfl_xor(ps, 32);
            s_run[qg] += ps;

#pragma unroll
            for (int c = 0; c < 2; ++c) {
                unsigned pk0[2], pk1[2];
#pragma unroll
                for (int rp = 0; rp < 2; ++rp) {
                    pk0[rp] = pkrtz(p[2 * c][2 * rp], p[2 * c][2 * rp + 1]);
                    pk1[rp] = pkrtz(p[2 * c + 1][2 * rp], p[2 * c + 1][2 * rp + 1]);
                }
                union { unsigned u[4]; f16x8 v; } au;
#pragma unroll
                for (int j = 0; j < 4; ++j) {
                    int src = l15 + ((((l4 & 1) << 1) + (j >> 1)) << 4);
                    unsigned g0 = (unsigned)__shfl((int)pk0[j & 1], src);
                    unsigned g1 = (unsigned)__shfl((int)pk1[j & 1], src);
                    au.u[j] = (l4 < 2) ? g0 : g1;
                }
                __builtin_amdgcn_s_setprio(1);
#pragma unroll
                for (int fo = 0; fo < 2; ++fo)
                    acc_o[qg][fo] = MFMA_F16(au.v, bv[c][fo], acc_o[qg][fo]);
                __builtin_amdgcn_s_setprio(0);
            }
        }
    }

#pragma unroll
    for (int qg = 0; qg < 2; ++qg) {
        float inv = 1.f / s_run[qg];
        float sinv[4];
#pragma unroll
        for (int r = 0; r < 4; ++r) sinv[r] = __shfl(inv, (l4 << 2) | r);
#pragma unroll
        for (int fo = 0; fo < 2; ++fo)
#pragma unroll
            for (int r = 0; r < 4; ++r) {
                int grow = b * 4096 + blk * 256 + qb + qg * 16 + l4 * 4 + r;
                o_ws[(size_t)grow * 256 + h * 32 + fo * 16 + l15] =
                    (half_t)(acc_o[qg][fo][r] * sinv[r]);
            }
    }
}

// ---------------------------------------------------------------------------
// proj GEMM (R15 8-wave engine): out = o @ proj_w + bias, fp32 out.
// BM=128, BN=256, BK=64, 512 threads (8 waves 4Mx2N), single LDS set 48KB.
// ---------------------------------------------------------------------------
__global__ __launch_bounds__(512) void gemm_proj(
    const half_t* __restrict__ A, const half_t* __restrict__ Bt,
    float* __restrict__ Dst, const float* __restrict__ bias) {
    __shared__ __align__(16) char smem[16384 + 32768];
    char* As = smem;
    char* Bs = smem + 16384;

    const int tid = threadIdx.x;
    const int lane = tid & 63, w = tid >> 6;
    const int l15 = lane & 15, l4 = lane >> 4;
    const int wrow = (w >> 1) * 32, wcol = (w & 1) * 128;
    const int bm0 = blockIdx.x * 128;
    const int bn0 = blockIdx.y * 256;
    const int pa = (l15 & 7) << 4;

    f32x4 acc[2][8];
#pragma unroll
    for (int i = 0; i < 2; ++i)
#pragma unroll
        for (int j = 0; j < 8; ++j) acc[i][j] = (f32x4){0.f, 0.f, 0.f, 0.f};

    f16x8 aReg[2], bReg[4];

    auto load_tile = [&](int kt) {
#pragma unroll
        for (int i = 0; i < 2; ++i) {
            int J = tid + i * 512;
            int row = J >> 3, c = (J & 7) ^ (row & 7);
            aReg[i] = *(const f16x8*)(A + (size_t)(bm0 + row) * 256 + kt * 64 + c * 8);
        }
#pragma unroll
        for (int i = 0; i < 4; ++i) {
            int J = tid + i * 512;
            int row = J >> 3, c = (J & 7) ^ (row & 7);
            bReg[i] = *(const f16x8*)(Bt + (size_t)(bn0 + row) * 256 + kt * 64 + c * 8);
        }
    };

    load_tile(0);
    for (int kt = 0; kt < 4; ++kt) {
        __syncthreads();
#pragma unroll
        for (int i = 0; i < 2; ++i) {
            int J = tid + i * 512;
            *(f16x8*)(As + J * 16) = aReg[i];
        }
#pragma unroll
        for (int i = 0; i < 4; ++i) {
            int J = tid + i * 512;
            *(f16x8*)(Bs + J * 16) = bReg[i];
        }
        __syncthreads();
        if (kt + 1 < 4) load_tile(kt + 1);
#pragma unroll
        for (int ki = 0; ki < 2; ++ki) {
            f16x8 af[2], bf[8];
#pragma unroll
            for (int mi = 0; mi < 2; ++mi) {
                int row = wrow + mi * 16 + l15;
                af[mi] = *(const f16x8*)(As + row * 128 + (((ki * 4 + l4) << 4) ^ pa));
            }
#pragma unroll
            for (int nj = 0; nj < 8; ++nj) {
                int row = wcol + nj * 16 + l15;
                bf[nj] = *(const f16x8*)(Bs + row * 128 + (((ki * 4 + l4) << 4) ^ pa));
            }
#pragma unroll
            for (int mi = 0; mi < 2; ++mi)
#pragma unroll
                for (int nj = 0; nj < 8; ++nj)
                    acc[mi][nj] = MFMA_F16(af[mi], bf[nj], acc[mi][nj]);
        }
    }

#pragma unroll
    for (int mi = 0; mi < 2; ++mi)
#pragma unroll
        for (int nj = 0; nj < 8; ++nj)
#pragma unroll
            for (int reg = 0; reg < 4; ++reg) {
                int grow = bm0 + wrow + mi * 16 + l4 * 4 + reg;
                int gcol = bn0 + wcol + nj * 16 + l15;
                Dst[(size_t)grow * 512 + gcol] = acc[mi][nj][reg] + bias[gcol];
            }
}

// ---------------------------------------------------------------------------
extern "C" void kernel_launch(void* const* d_in, const int* in_sizes, int n_in,
                              void* d_out, int out_size, void* d_ws, size_t ws_size,
                              hipStream_t stream) {
    const float* x        = (const float*)d_in[0];
    const float* reduce_w = (const float*)d_in[1];
    const float* qkv_w    = (const float*)d_in[2];
    const float* proj_w   = (const float*)d_in[3];
    const float* proj_b   = (const float*)d_in[4];
    char* ws = (char*)d_ws;

    half_t* o_buf = (half_t*)ws;                       // o [16384][256], 8MB
    half_t* pw_t  = (half_t*)(ws + 8388608);           // proj_w^T [512][256]
    half_t* W3    = (half_t*)(ws + 8650752);           // [8][96][512] fp16

    // prep: W3-GEMM (48) + pw_t (32)
    prep<<<80, 256, 0, stream>>>(qkv_w, reduce_w, proj_w, pw_t, W3);
    // fused qkv + attention: 512 WGs x 512 thr; heads of a block same-XCD
    qkv_attn<<<512, 512, 0, stream>>>(x, W3, o_buf);
    // out = o @ proj_w + proj_b, M=16384 N=512 K=256
    gemm_proj<<<dim3(128, 2), 512, 0, stream>>>(o_buf, pw_t, (float*)d_out, proj_b);
}